// Round 5
// baseline (2092.973 us; speedup 1.0000x reference)
//
#include <hip/hip_runtime.h>
#include <hip/hip_bf16.h>
#include <stdint.h>

#define GRIDN 48
#define F 2304
#define C 128
#define H 8
#define DH 16
#define NB 2          // batch (meshes)
#define WID 256
#define NLV 49        // BFS levels for GRID=48, anchor at (24,24)
#define FLOOD_BLOCKS 96

typedef __hip_bfloat16 bf16;

__device__ __forceinline__ float b2f(bf16 v) { return __bfloat162float(v); }

// ---------------------------------------------------------------- K-1: input dtype detector
__global__ void k_detect(const void* __restrict__ x, int* __restrict__ flag) {
    __shared__ int bad;
    if (threadIdx.x == 0) bad = 0;
    __syncthreads();
    const bf16* xb = (const bf16*)x;
    int insane = 0;
    #pragma unroll
    for (int i = 0; i < 8; ++i) {
        float v = b2f(xb[threadIdx.x * 8 + i]);
        if (!(fabsf(v) < 1e10f)) insane = 1;
    }
    if (insane) atomicOr(&bad, 1);
    __syncthreads();
    if (threadIdx.x == 0) *flag = bad;
}

// ---------------------------------------------------------------- K0: ring permutation tables
// permIdx[face]=sorted pos; invPerm[pos]=face; startOfPos[pos]=ringStart[level(pos)];
// ringStart[lv] prefix table; zeroes the grid-barrier counter.
__global__ void k_perm(int* __restrict__ permIdx, int* __restrict__ invPerm,
                       int* __restrict__ startOfPos, int* __restrict__ ringStart,
                       int* __restrict__ gcount) {
    __shared__ int cnt[NLV], start[NLV], rs0[NLV];
    int t = threadIdx.x;
    if (t < NLV) cnt[t] = 0;
    if (t == 0) *gcount = 0;
    __syncthreads();
    for (int f = t; f < F; f += 256) {
        int d = abs(f / GRIDN - GRIDN / 2) + abs(f % GRIDN - GRIDN / 2);
        atomicAdd(&cnt[d], 1);
    }
    __syncthreads();
    if (t == 0) {
        int s = 0;
        for (int l = 0; l < NLV; ++l) { start[l] = s; rs0[l] = s; ringStart[l] = s; s += cnt[l]; }
        ringStart[NLV] = s;
    }
    __syncthreads();
    for (int f = t; f < F; f += 256) {
        int d = abs(f / GRIDN - GRIDN / 2) + abs(f % GRIDN - GRIDN / 2);
        int p = atomicAdd(&start[d], 1);
        permIdx[f] = p;
        invPerm[p] = f;
        startOfPos[p] = rs0[d];
    }
}

// ---------------------------------------------------------------- K0b: weights -> fp32
struct WSeg { const void* src; int off; int cnt; };
struct WSegs { WSeg s[14]; };

__global__ void k_convert(WSegs segs, const int* __restrict__ flag,
                          float* __restrict__ dst, int total) {
    int i = blockIdx.x * blockDim.x + threadIdx.x;
    if (i >= total) return;
    bool f32 = (*flag != 0);
    #pragma unroll 1
    for (int j = 0; j < 14; ++j) {
        int off = segs.s[j].off, cnt = segs.s[j].cnt;
        if (i >= off && i < off + cnt) {
            int k = i - off;
            dst[i] = f32 ? ((const float*)segs.s[j].src)[k]
                         : b2f(((const bf16*)segs.s[j].src)[k]);
            return;
        }
    }
}

// ---------------------------------------------------------------- K1: x[B,C,F] -> cur[B,F,C]
__global__ void k_transpose_in(const void* __restrict__ x, const int* __restrict__ flag,
                               float* __restrict__ cur) {
    __shared__ float tile[32][33];
    bool f32 = (*flag != 0);
    int b = blockIdx.z;
    int f0 = blockIdx.x * 32, c0 = blockIdx.y * 32;
    int tx = threadIdx.x, ty = threadIdx.y;
    #pragma unroll
    for (int i = 0; i < 4; ++i) {
        int c = c0 + ty + i * 8;
        size_t idx = ((size_t)b * C + c) * F + f0 + tx;
        tile[ty + i * 8][tx] = f32 ? ((const float*)x)[idx] : b2f(((const bf16*)x)[idx]);
    }
    __syncthreads();
    #pragma unroll
    for (int i = 0; i < 4; ++i) {
        int f = f0 + ty + i * 8;
        cur[((size_t)b * F + f) * C + c0 + tx] = tile[tx][ty + i * 8];
    }
}

// ---------------------------------------------------------------- K2: projections; khT/vhT [mesh][c][F] ring-permuted
__global__ __launch_bounds__(128) void k_proj_init(
        const float* __restrict__ cur, const int* __restrict__ permIdx,
        const float* __restrict__ Wq, const float* __restrict__ Wk, const float* __restrict__ Wv,
        float* __restrict__ qh, float* __restrict__ khT, float* __restrict__ vhT) {
    __shared__ float rows[8][C];
    int r0 = blockIdx.x * 8;
    int tid = threadIdx.x;
    #pragma unroll
    for (int r = 0; r < 8; ++r) rows[r][tid] = cur[(size_t)(r0 + r) * C + tid];
    __syncthreads();
    float aq[8], ak[8], av[8];
    #pragma unroll
    for (int r = 0; r < 8; ++r) { aq[r] = 0.f; ak[r] = 0.f; av[r] = 0.f; }
    for (int k = 0; k < C; ++k) {
        float wq = Wq[k * C + tid];
        float wk = Wk[k * C + tid];
        float wv = Wv[k * C + tid];
        #pragma unroll
        for (int r = 0; r < 8; ++r) {
            float xv = rows[r][k];
            aq[r] = fmaf(xv, wq, aq[r]);
            ak[r] = fmaf(xv, wk, ak[r]);
            av[r] = fmaf(xv, wv, av[r]);
        }
    }
    const float scale = 0.25f;
    #pragma unroll
    for (int r = 0; r < 8; ++r) {
        int grow = r0 + r;
        int mesh = grow / F, face = grow % F;
        int p = permIdx[face];
        qh[(size_t)grow * C + tid] = aq[r] * scale;
        khT[((size_t)mesh * C + tid) * F + p] = ak[r];
        vhT[((size_t)mesh * C + tid) * F + p] = av[r];
    }
}

// ---------------------------------------------------------------- K3a: suffix attention (initial K/V), 4 queries/block
// For query at sorted pos p (level lv): keys pos >= startOfPos[p] use INITIAL K/V.
// Runs before any K/V update, so khT/vhT ARE the initial values here.
__global__ __launch_bounds__(256) void k_suffix(
        const int* __restrict__ invPerm, const int* __restrict__ startOfPos,
        const float* __restrict__ qh_all,
        const float* __restrict__ khT, const float* __restrict__ vhT,
        float* __restrict__ sufM, float* __restrict__ sufL, float* __restrict__ sufA) {
    int bx = blockIdx.x;
    int mesh = bx & 1;
    int p0 = (bx >> 1) * 4;
    int tid = threadIdx.x;
    __shared__ float sQh[4][C];
    __shared__ int sFace[4], sStart[4];
    if (tid < 4) {
        sFace[tid] = invPerm[p0 + tid];
        sStart[tid] = startOfPos[p0 + tid];
    }
    __syncthreads();
    {
        int j = tid >> 7, ch = tid & 127;
        sQh[j][ch]     = qh_all[((size_t)mesh * F + sFace[j]) * C + ch];
        sQh[j + 2][ch] = qh_all[((size_t)mesh * F + sFace[j + 2]) * C + ch];
    }
    __syncthreads();
    int head = tid >> 5, sub = tid & 31;
    float q[4][DH];
    #pragma unroll
    for (int j = 0; j < 4; ++j)
        #pragma unroll
        for (int d = 0; d < DH; ++d) q[j][d] = sQh[j][head * DH + d];
    const float* Kb = khT + ((size_t)mesh * C + head * DH) * F;
    const float* Vb = vhT + ((size_t)mesh * C + head * DH) * F;
    float m[4], l[4], acc[4][DH];
    #pragma unroll
    for (int j = 0; j < 4; ++j) {
        m[j] = -1e30f; l[j] = 0.f;
        #pragma unroll
        for (int d = 0; d < DH; ++d) acc[j][d] = 0.f;
    }
    int st0 = sStart[0], st1 = sStart[1], st2 = sStart[2], st3 = sStart[3];
    for (int base = st0 & ~127; base < F; base += 128) {
        int p4 = base + 4 * sub;
        float sc[4][4];
        #pragma unroll
        for (int j = 0; j < 4; ++j)
            #pragma unroll
            for (int c = 0; c < 4; ++c) sc[j][c] = 0.f;
        #pragma unroll
        for (int d = 0; d < DH; ++d) {
            float4 kk = *(const float4*)(Kb + d * F + p4);
            #pragma unroll
            for (int j = 0; j < 4; ++j) {
                float a = q[j][d];
                sc[j][0] = fmaf(a, kk.x, sc[j][0]); sc[j][1] = fmaf(a, kk.y, sc[j][1]);
                sc[j][2] = fmaf(a, kk.z, sc[j][2]); sc[j][3] = fmaf(a, kk.w, sc[j][3]);
            }
        }
        // mask keys before each query's suffix start
        #pragma unroll
        for (int c = 0; c < 4; ++c) {
            int pos = p4 + c;
            if (pos < st0) sc[0][c] = -1e30f;
            if (pos < st1) sc[1][c] = -1e30f;
            if (pos < st2) sc[2][c] = -1e30f;
            if (pos < st3) sc[3][c] = -1e30f;
        }
        float cj[4], px[4][4];
        #pragma unroll
        for (int j = 0; j < 4; ++j) {
            float mx = fmaxf(fmaxf(sc[j][0], sc[j][1]), fmaxf(sc[j][2], sc[j][3]));
            float mn = fmaxf(m[j], mx);
            cj[j] = __expf(m[j] - mn);
            px[j][0] = __expf(sc[j][0] - mn); px[j][1] = __expf(sc[j][1] - mn);
            px[j][2] = __expf(sc[j][2] - mn); px[j][3] = __expf(sc[j][3] - mn);
            l[j] = fmaf(l[j], cj[j], px[j][0] + px[j][1] + px[j][2] + px[j][3]);
            m[j] = mn;
        }
        #pragma unroll
        for (int d = 0; d < DH; ++d) {
            float4 vv = *(const float4*)(Vb + d * F + p4);
            #pragma unroll
            for (int j = 0; j < 4; ++j) {
                float w = fmaf(px[j][0], vv.x, fmaf(px[j][1], vv.y, fmaf(px[j][2], vv.z, px[j][3] * vv.w)));
                acc[j][d] = fmaf(acc[j][d], cj[j], w);
            }
        }
    }
    // butterfly merge across 32 lanes
    #pragma unroll
    for (int w = 16; w >= 1; w >>= 1) {
        #pragma unroll
        for (int j = 0; j < 4; ++j) {
            float mo = __shfl_xor(m[j], w), lo = __shfl_xor(l[j], w);
            float mn = fmaxf(m[j], mo);
            float ca = __expf(m[j] - mn), cb = __expf(mo - mn);
            l[j] = l[j] * ca + lo * cb;
            #pragma unroll
            for (int d = 0; d < DH; ++d) {
                float ao = __shfl_xor(acc[j][d], w);
                acc[j][d] = acc[j][d] * ca + ao * cb;
            }
            m[j] = mn;
        }
    }
    if (sub == 0) {
        #pragma unroll
        for (int j = 0; j < 4; ++j) {
            size_t sb = ((size_t)mesh * F + p0 + j) * H + head;
            sufM[sb] = m[j];
            sufL[sb] = l[j];
            #pragma unroll
            for (int d = 0; d < DH; ++d) sufA[sb * 16 + d] = acc[j][d];
        }
    }
}

// ---------------------------------------------------------------- grid barrier (monotone counter)
// NOTE: relies on all FLOOD_BLOCKS blocks being co-resident (96 small blocks on
// 256 CUs, nothing else running in the serialized stream) — G16 caveat accepted.
__device__ __forceinline__ void grid_barrier(int* gcount, int target) {
    __threadfence();                 // each thread drains its own stores to L2
    __syncthreads();
    if (threadIdx.x == 0) {
        atomicAdd(gcount, 1);        // device-scope by default
        while (__hip_atomic_load(gcount, __ATOMIC_RELAXED, __HIP_MEMORY_SCOPE_AGENT) < target)
            __builtin_amdgcn_s_sleep(8);
    }
    __syncthreads();
    __threadfence();                 // invalidate L1 before reading peers' data
}

// ---------------------------------------------------------------- K3b: persistent flood fill (49 levels, prefix-only)
__global__ __launch_bounds__(256) void k_flood(
        const int* __restrict__ ringStart, const int* __restrict__ invPerm,
        const float* __restrict__ qh_all, float* __restrict__ cur,
        float* __restrict__ khT, float* __restrict__ vhT,
        const float* __restrict__ sufM, const float* __restrict__ sufL, const float* __restrict__ sufA,
        const float* __restrict__ Wk, const float* __restrict__ Wv, const float* __restrict__ Wo,
        int* gcount) {
    int bx = blockIdx.x, tid = threadIdx.x;
    int head = tid >> 5, sub = tid & 31;
    __shared__ float sQh[2][C], sQ[2][C], sPA[2][C], sP[2][C], sNew[2][C];
    __shared__ float sM[2][H], sL[2][H];
    __shared__ int sF[2];
    for (int lv = 0; lv < NLV; ++lv) {
        int rs = ringStart[lv], re = ringStart[lv + 1];
        int items = 2 * ((re - rs + 1) >> 1);
        if (bx < items) {
            int mesh = bx & 1;
            int p0 = rs + 2 * (bx >> 1);
            int p1 = p0 + 1;
            bool a1 = p1 < re;
            int p1c = a1 ? p1 : p0;
            if (tid < 2) sF[tid] = invPerm[tid == 0 ? p0 : p1c];
            __syncthreads();
            size_t row0 = ((size_t)mesh * F + sF[0]) * C;
            size_t row1 = ((size_t)mesh * F + sF[1]) * C;
            {
                int j = tid >> 7, ch = tid & 127;
                size_t r = j ? row1 : row0;
                sQ[j][ch]  = cur[r + ch];
                sQh[j][ch] = qh_all[r + ch];
            }
            __syncthreads();
            float q0[DH], q1[DH];
            #pragma unroll
            for (int d = 0; d < DH; ++d) { q0[d] = sQh[0][head * DH + d]; q1[d] = sQh[1][head * DH + d]; }
            const float* Kb = khT + ((size_t)mesh * C + head * DH) * F;
            const float* Vb = vhT + ((size_t)mesh * C + head * DH) * F;
            float m0 = -1e30f, l0 = 0.f, m1 = -1e30f, l1 = 0.f;
            float acc0[DH], acc1[DH];
            #pragma unroll
            for (int d = 0; d < DH; ++d) { acc0[d] = 0.f; acc1[d] = 0.f; }
            for (int base = 0; base < rs; base += 128) {
                int p4 = base + 4 * sub;
                float sx0 = 0, sy0 = 0, sz0 = 0, sw0 = 0;
                float sx1 = 0, sy1 = 0, sz1 = 0, sw1 = 0;
                #pragma unroll
                for (int d = 0; d < DH; ++d) {
                    float4 kk = *(const float4*)(Kb + d * F + p4);
                    float a = q0[d], b = q1[d];
                    sx0 = fmaf(a, kk.x, sx0); sy0 = fmaf(a, kk.y, sy0);
                    sz0 = fmaf(a, kk.z, sz0); sw0 = fmaf(a, kk.w, sw0);
                    sx1 = fmaf(b, kk.x, sx1); sy1 = fmaf(b, kk.y, sy1);
                    sz1 = fmaf(b, kk.z, sz1); sw1 = fmaf(b, kk.w, sw1);
                }
                if (base + 128 > rs) {   // tail chunk: mask keys at pos >= rs
                    if (p4 + 0 >= rs) { sx0 = -1e30f; sx1 = -1e30f; }
                    if (p4 + 1 >= rs) { sy0 = -1e30f; sy1 = -1e30f; }
                    if (p4 + 2 >= rs) { sz0 = -1e30f; sz1 = -1e30f; }
                    if (p4 + 3 >= rs) { sw0 = -1e30f; sw1 = -1e30f; }
                }
                float mx0 = fmaxf(fmaxf(sx0, sy0), fmaxf(sz0, sw0));
                float mn0 = fmaxf(m0, mx0);
                float c0 = __expf(m0 - mn0);
                float px0 = __expf(sx0 - mn0), py0 = __expf(sy0 - mn0);
                float pz0 = __expf(sz0 - mn0), pw0 = __expf(sw0 - mn0);
                l0 = fmaf(l0, c0, px0 + py0 + pz0 + pw0);
                m0 = mn0;
                float mx1 = fmaxf(fmaxf(sx1, sy1), fmaxf(sz1, sw1));
                float mn1 = fmaxf(m1, mx1);
                float c1e = __expf(m1 - mn1);
                float px1 = __expf(sx1 - mn1), py1 = __expf(sy1 - mn1);
                float pz1 = __expf(sz1 - mn1), pw1 = __expf(sw1 - mn1);
                l1 = fmaf(l1, c1e, px1 + py1 + pz1 + pw1);
                m1 = mn1;
                #pragma unroll
                for (int d = 0; d < DH; ++d) {
                    float4 vv = *(const float4*)(Vb + d * F + p4);
                    float w0 = fmaf(px0, vv.x, fmaf(py0, vv.y, fmaf(pz0, vv.z, pw0 * vv.w)));
                    float w1 = fmaf(px1, vv.x, fmaf(py1, vv.y, fmaf(pz1, vv.z, pw1 * vv.w)));
                    acc0[d] = fmaf(acc0[d], c0, w0);
                    acc1[d] = fmaf(acc1[d], c1e, w1);
                }
            }
            #pragma unroll
            for (int w = 16; w >= 1; w >>= 1) {
                float mo = __shfl_xor(m0, w), lo = __shfl_xor(l0, w);
                float mn = fmaxf(m0, mo);
                float ca = __expf(m0 - mn), cb = __expf(mo - mn);
                l0 = l0 * ca + lo * cb;
                #pragma unroll
                for (int d = 0; d < DH; ++d) {
                    float ao = __shfl_xor(acc0[d], w);
                    acc0[d] = acc0[d] * ca + ao * cb;
                }
                m0 = mn;
                mo = __shfl_xor(m1, w); lo = __shfl_xor(l1, w);
                mn = fmaxf(m1, mo);
                ca = __expf(m1 - mn); cb = __expf(mo - mn);
                l1 = l1 * ca + lo * cb;
                #pragma unroll
                for (int d = 0; d < DH; ++d) {
                    float ao = __shfl_xor(acc1[d], w);
                    acc1[d] = acc1[d] * ca + ao * cb;
                }
                m1 = mn;
            }
            if (sub == 0) {
                sM[0][head] = m0; sL[0][head] = l0;
                sM[1][head] = m1; sL[1][head] = l1;
                #pragma unroll
                for (int d = 0; d < DH; ++d) {
                    sPA[0][head * DH + d] = acc0[d];
                    sPA[1][head * DH + d] = acc1[d];
                }
            }
            __syncthreads();
            {   // merge prefix partial with suffix partial, normalize
                int j = tid >> 7, ch = tid & 127, h = ch >> 4, d = ch & 15;
                int pq = j ? p1c : p0;
                size_t sb = ((size_t)mesh * F + pq) * H + h;
                float mp = sM[j][h], lp = sL[j][h];
                float ms = sufM[sb], ls = sufL[sb];
                float mm = fmaxf(mp, ms);
                float e1 = __expf(mp - mm), e2 = __expf(ms - mm);
                float num = fmaf(sPA[j][ch], e1, sufA[sb * 16 + d] * e2);
                float den = fmaf(lp, e1, ls * e2);
                sP[j][ch] = num / den;
            }
            __syncthreads();
            {   // out-proj + resid
                int j = tid >> 7, ch = tid & 127;
                float o = 0.f;
                for (int k = 0; k < C; ++k) o = fmaf(sP[j][k], Wo[k * C + ch], o);
                float nv = sQ[j][ch] + o;
                sNew[j][ch] = nv;
                if (j == 0 || a1) cur[(j ? row1 : row0) + ch] = nv;
            }
            __syncthreads();
            for (int j = 0; j < 2; ++j) {   // K/V column refresh at own ring positions
                if (j == 1 && !a1) break;
                int pq = j ? p1 : p0;
                if (tid < C) {
                    float a = 0.f;
                    for (int k = 0; k < C; ++k) a = fmaf(sNew[j][k], Wk[k * C + tid], a);
                    khT[((size_t)mesh * C + tid) * F + pq] = a;
                } else {
                    int c2 = tid - C;
                    float a = 0.f;
                    for (int k = 0; k < C; ++k) a = fmaf(sNew[j][k], Wv[k * C + c2], a);
                    vhT[((size_t)mesh * C + c2) * F + pq] = a;
                }
            }
        }
        grid_barrier(gcount, FLOOD_BLOCKS * (lv + 1));
    }
}

// ---------------------------------------------------------------- K4: MLP + sigmoid (b128 LDS reads)
__global__ __launch_bounds__(256) void k_mlp(
        const float* __restrict__ cur,
        const float* __restrict__ W1, const float* __restrict__ b1,
        const float* __restrict__ W2, const float* __restrict__ b2,
        const float* __restrict__ W3, const float* __restrict__ b3,
        const float* __restrict__ W4, const float* __restrict__ b4,
        const float* __restrict__ W5, const float* __restrict__ b5,
        float* __restrict__ out_scores) {
    __shared__ __align__(16) float sIn[8][C];
    __shared__ __align__(16) float sA[8][WID];
    __shared__ __align__(16) float sB[8][WID];
    int tid = threadIdx.x;
    int r0 = blockIdx.x * 8;
    for (int i = tid; i < 8 * C; i += 256) sIn[i >> 7][i & 127] = cur[(size_t)r0 * C + i];
    __syncthreads();
    {
        float a[8];
        #pragma unroll
        for (int r = 0; r < 8; ++r) a[r] = 0.f;
        for (int k = 0; k < C; k += 4) {
            float w0 = W1[(k + 0) * WID + tid], w1 = W1[(k + 1) * WID + tid];
            float w2 = W1[(k + 2) * WID + tid], w3 = W1[(k + 3) * WID + tid];
            #pragma unroll
            for (int r = 0; r < 8; ++r) {
                float4 xv = *(const float4*)&sIn[r][k];
                a[r] = fmaf(xv.x, w0, fmaf(xv.y, w1, fmaf(xv.z, w2, fmaf(xv.w, w3, a[r]))));
            }
        }
        float bias = b1[tid];
        #pragma unroll
        for (int r = 0; r < 8; ++r) sA[r][tid] = fmaxf(a[r] + bias, 0.f);
    }
    __syncthreads();
    {
        float a[8];
        #pragma unroll
        for (int r = 0; r < 8; ++r) a[r] = 0.f;
        for (int k = 0; k < WID; k += 4) {
            float w0 = W2[(k + 0) * WID + tid], w1 = W2[(k + 1) * WID + tid];
            float w2 = W2[(k + 2) * WID + tid], w3 = W2[(k + 3) * WID + tid];
            #pragma unroll
            for (int r = 0; r < 8; ++r) {
                float4 xv = *(const float4*)&sA[r][k];
                a[r] = fmaf(xv.x, w0, fmaf(xv.y, w1, fmaf(xv.z, w2, fmaf(xv.w, w3, a[r]))));
            }
        }
        float bias = b2[tid];
        #pragma unroll
        for (int r = 0; r < 8; ++r) sB[r][tid] = fmaxf(a[r] + bias, 0.f);
    }
    __syncthreads();
    {
        float a[8];
        #pragma unroll
        for (int r = 0; r < 8; ++r) a[r] = 0.f;
        for (int k = 0; k < WID; k += 4) {
            float w0 = W3[(k + 0) * WID + tid], w1 = W3[(k + 1) * WID + tid];
            float w2 = W3[(k + 2) * WID + tid], w3 = W3[(k + 3) * WID + tid];
            #pragma unroll
            for (int r = 0; r < 8; ++r) {
                float4 xv = *(const float4*)&sB[r][k];
                a[r] = fmaf(xv.x, w0, fmaf(xv.y, w1, fmaf(xv.z, w2, fmaf(xv.w, w3, a[r]))));
            }
        }
        float bias = b3[tid];
        #pragma unroll
        for (int r = 0; r < 8; ++r) sA[r][tid] = fmaxf(a[r] + bias, 0.f);
    }
    __syncthreads();
    {
        float a[8];
        #pragma unroll
        for (int r = 0; r < 8; ++r) a[r] = 0.f;
        for (int k = 0; k < WID; k += 4) {
            float w0 = W4[(k + 0) * WID + tid], w1 = W4[(k + 1) * WID + tid];
            float w2 = W4[(k + 2) * WID + tid], w3 = W4[(k + 3) * WID + tid];
            #pragma unroll
            for (int r = 0; r < 8; ++r) {
                float4 xv = *(const float4*)&sA[r][k];
                a[r] = fmaf(xv.x, w0, fmaf(xv.y, w1, fmaf(xv.z, w2, fmaf(xv.w, w3, a[r]))));
            }
        }
        float bias = b4[tid];
        #pragma unroll
        for (int r = 0; r < 8; ++r) sB[r][tid] = fmaxf(a[r] + bias, 0.f);
    }
    __syncthreads();
    if (tid < 8) {
        float a = b5[0];
        for (int k = 0; k < WID; ++k) a = fmaf(sB[tid][k], W5[k], a);
        out_scores[r0 + tid] = 1.f / (1.f + __expf(-a));
    }
}

// ---------------------------------------------------------------- K5: cur[B,F,C] -> out0[B,C,F]
__global__ void k_transpose_out(const float* __restrict__ cur, float* __restrict__ out) {
    __shared__ float tile[32][33];
    int b = blockIdx.z;
    int f0 = blockIdx.x * 32, c0 = blockIdx.y * 32;
    int tx = threadIdx.x, ty = threadIdx.y;
    #pragma unroll
    for (int i = 0; i < 4; ++i) {
        int f = f0 + ty + i * 8;
        tile[ty + i * 8][tx] = cur[((size_t)b * F + f) * C + c0 + tx];
    }
    __syncthreads();
    #pragma unroll
    for (int i = 0; i < 4; ++i) {
        int c = c0 + ty + i * 8;
        out[((size_t)b * C + c) * F + f0 + tx] = tile[tx][ty + i * 8];
    }
}

// ----------------------------------------------------------------
extern "C" void kernel_launch(void* const* d_in, const int* in_sizes, int n_in,
                              void* d_out, int out_size, void* d_ws, size_t ws_size,
                              hipStream_t stream) {
    const size_t n = (size_t)NB * F * C;          // 589824
    float* cur  = (float*)d_ws;
    float* qh   = cur + n;
    float* khT  = qh + n;
    float* vhT  = khT + n;
    float* sufM = vhT + n;                        // [NB][F][H]
    float* sufL = sufM + (size_t)NB * F * H;
    float* sufA = sufL + (size_t)NB * F * H;      // [NB][F][H][16]
    float* wbuf = sufA + (size_t)NB * F * H * 16;
    int*   permIdx    = (int*)(wbuf + 296193 + 3);
    int*   invPerm    = permIdx + F;
    int*   startOfPos = invPerm + F;
    int*   ringStartD = startOfPos + F;
    int*   flag       = ringStartD + NLV + 1;
    int*   gcount     = flag + 1;

    const int oWq = 0,       oWk = 16384,  oWv = 32768,  oWo = 49152;
    const int oW1 = 65536,   oB1 = 98304;
    const int oW2 = 98560,   oB2 = 164096;
    const int oW3 = 164352,  oB3 = 229888;
    const int oW4 = 230144,  oB4 = 295680;
    const int oW5 = 295936,  oB5 = 296192;
    const int wtot = 296193;

    WSegs segs = {{
        { d_in[1],  oWq, 16384 }, { d_in[2],  oWk, 16384 },
        { d_in[3],  oWv, 16384 }, { d_in[4],  oWo, 16384 },
        { d_in[5],  oW1, 32768 }, { d_in[6],  oB1, 256 },
        { d_in[7],  oW2, 65536 }, { d_in[8],  oB2, 256 },
        { d_in[9],  oW3, 65536 }, { d_in[10], oB3, 256 },
        { d_in[11], oW4, 65536 }, { d_in[12], oB4, 256 },
        { d_in[13], oW5, 256 },   { d_in[14], oB5, 1 },
    }};

    float* out0 = (float*)d_out;                  // [B,C,F] fp32
    float* out1 = out0 + (size_t)NB * C * F;      // [B,F,1] fp32

    k_detect<<<1, 256, 0, stream>>>(d_in[0], flag);
    k_perm<<<1, 256, 0, stream>>>(permIdx, invPerm, startOfPos, ringStartD, gcount);
    k_convert<<<(wtot + 255) / 256, 256, 0, stream>>>(segs, flag, wbuf, wtot);
    k_transpose_in<<<dim3(F / 32, C / 32, NB), dim3(32, 8), 0, stream>>>(d_in[0], flag, cur);
    k_proj_init<<<(NB * F) / 8, 128, 0, stream>>>(cur, permIdx, wbuf + oWq, wbuf + oWk, wbuf + oWv,
                                                  qh, khT, vhT);
    k_suffix<<<NB * (F / 4), 256, 0, stream>>>(invPerm, startOfPos, qh, khT, vhT, sufM, sufL, sufA);
    k_flood<<<FLOOD_BLOCKS, 256, 0, stream>>>(ringStartD, invPerm, qh, cur, khT, vhT,
                                              sufM, sufL, sufA,
                                              wbuf + oWk, wbuf + oWv, wbuf + oWo, gcount);
    k_mlp<<<(NB * F) / 8, 256, 0, stream>>>(cur, wbuf + oW1, wbuf + oB1, wbuf + oW2, wbuf + oB2,
                                            wbuf + oW3, wbuf + oB3, wbuf + oW4, wbuf + oB4,
                                            wbuf + oW5, wbuf + oB5, out1);
    k_transpose_out<<<dim3(F / 32, C / 32, NB), dim3(32, 8), 0, stream>>>(cur, out0);
}